// Round 1
// baseline (78.666 us; speedup 1.0000x reference)
//
#include <hip/hip_runtime.h>

#define N_PTS   4096
#define N_BATCH 16
#define INV_CNT (1.0f / (2.0f * N_BATCH * N_PTS))
#define AROW_BYTES ((size_t)2 * N_BATCH * N_PTS * 16 * 2)   // 4 MB
#define NBLK    512                // main-kernel blocks

typedef _Float16 f16x8  __attribute__((ext_vector_type(8)));
#define AS1 __attribute__((address_space(1)))
#define AS3 __attribute__((address_space(3)))

// 32x32x16 f16 MFMA, K-slot packing (split o = oh + ol, p = ph + pl in f16):
//   A-row (opposite point o): [-2oh_x,-2oh_y,-2oh_z, -2ol_x,-2ol_y,-2ol_z,
//                              -2oh_x,-2oh_y | -2oh_z, o2h, o2l, 0...]
//   B-col (query p):          [ph_x,ph_y,ph_z, ph_x,ph_y,ph_z, pl_x,pl_y |
//                              pl_z, 1, 1, 0...]
//   => C = |o|^2 - 2 o.p   (dropped ol.pl ~2^-22; verified R5-R14, absmax 0.0)
__global__ __launch_bounds__(256) void prep_kernel(
    const float* __restrict__ tpl, const float* __restrict__ src,
    _Float16* __restrict__ arow, float* __restrict__ out) {
    int pt = blockIdx.x * 256 + threadIdx.x;          // 0..131071 (T set, then S set)
    if (pt == 0) out[0] = 0.0f;                       // fallback path runs after
    const float* p = (pt < 65536 ? tpl : src) + (size_t)(pt & 65535) * 3;
    float x = p[0], y = p[1], z = p[2];
    float o2 = fmaf(x, x, fmaf(y, y, z * z));
    _Float16 xh = (_Float16)x, yh = (_Float16)y, zh = (_Float16)z;
    _Float16 xl = (_Float16)(x - (float)xh);
    _Float16 yl = (_Float16)(y - (float)yh);
    _Float16 zl = (_Float16)(z - (float)zh);
    _Float16 o2h = (_Float16)o2;
    _Float16 o2l = (_Float16)(o2 - (float)o2h);
    const _Float16 m2 = (_Float16)-2.0f;              // exact power-of-2 scale
    f16x8 v0, v1;
    v0[0] = m2 * xh; v0[1] = m2 * yh; v0[2] = m2 * zh;
    v0[3] = m2 * xl; v0[4] = m2 * yl; v0[5] = m2 * zl;
    v0[6] = m2 * xh; v0[7] = m2 * yh;
    v1[0] = m2 * zh; v1[1] = o2h; v1[2] = o2l;
    v1[3] = (_Float16)0.0f; v1[4] = (_Float16)0.0f; v1[5] = (_Float16)0.0f;
    v1[6] = (_Float16)0.0f; v1[7] = (_Float16)0.0f;
    *(f16x8*)(arow + (size_t)pt * 16)     = v0;
    *(f16x8*)(arow + (size_t)pt * 16 + 8) = v1;
}

// ---- asm blocks (chunk-local register state only). Banks: D0..D3 =
// v[32:47]/v[48:63]/v[64:79]/v[80:95]; zero-C = v[96:111], re-zeroed per
// chunk. R15: wave <-> work mapping transposed -- each wave handles ALL
// 256 block queries (8 B-frags) against ITS OWN quarter of each A-chunk.
// LDS reads /4 (4 ds_read_b128 per chunk vs 16) and the per-chunk
// s_barriers are gone: a wave stages and reads only its own 4 KB quarter,
// so the pipeline is purely per-wave (vmcnt ring). Cross-wave min-combine
// happens once in the epilogue via LDS. ----
#define FD(a,x,y) "v_min3_f32 %[" #a "], v" #x ", v" #y ", %[" #a "]\n\t"
#define FOLD_D0(p,q) FD(p,32,33) FD(q,34,35) FD(p,36,37) FD(q,38,39) \
                     FD(p,40,41) FD(q,42,43) FD(p,44,45) FD(q,46,47)
#define FOLD_D1(p,q) FD(p,48,49) FD(q,50,51) FD(p,52,53) FD(q,54,55) \
                     FD(p,56,57) FD(q,58,59) FD(p,60,61) FD(q,62,63)
#define FOLD_D2(p,q) FD(p,64,65) FD(q,66,67) FD(p,68,69) FD(q,70,71) \
                     FD(p,72,73) FD(q,74,75) FD(p,76,77) FD(q,78,79)
#define FOLD_D3(p,q) FD(p,80,81) FD(q,82,83) FD(p,84,85) FD(q,86,87) \
                     FD(p,88,89) FD(q,90,91) FD(p,92,93) FD(q,94,95)
#define MFD0(d,b) "v_mfma_f32_32x32x16_f16 v[32:47], %[" #d "], %[" #b "], v[96:111]\n\t"
#define MFD1(d,b) "v_mfma_f32_32x32x16_f16 v[48:63], %[" #d "], %[" #b "], v[96:111]\n\t"
#define MFD2(d,b) "v_mfma_f32_32x32x16_f16 v[64:79], %[" #d "], %[" #b "], v[96:111]\n\t"
#define MFD3(d,b) "v_mfma_f32_32x32x16_f16 v[80:95], %[" #d "], %[" #b "], v[96:111]\n\t"
#define DSR(d,off) "ds_read_b128 %[" #d "], %[dsa] offset:" #off "\n\t"
#define WL(n) "s_waitcnt lgkmcnt(" #n ")\n\t"
#define ZM(r) "v_mov_b32 v" #r ", 0\n\t"
#define NOP3 "s_nop 7\n\t" "s_nop 7\n\t" "s_nop 7\n\t"

// One A-tile (32 opposite pts, frag d) vs all 8 B-frags (256 queries).
// Round 1: bf0..bf3 -> D0..D3 (NOP3 guards first fold's MFMA->VALU RAW);
// round 2: bf4..bf7 reuse banks, folds interleave (>=48cyc spacing).
#define TILE(d,wl) \
  WL(wl) \
  MFD0(d,bf0) MFD1(d,bf1) MFD2(d,bf2) MFD3(d,bf3) \
  NOP3 \
  FOLD_D0(acc0,acc1)   MFD0(d,bf4) \
  FOLD_D1(acc2,acc3)   MFD1(d,bf5) \
  FOLD_D2(acc4,acc5)   MFD2(d,bf6) \
  FOLD_D3(acc6,acc7)   MFD3(d,bf7) \
  FOLD_D0(acc8,acc9) FOLD_D1(acc10,acc11) FOLD_D2(acc12,acc13) FOLD_D3(acc14,acc15)

// Grid (16,16,2) = 512 blocks x 4 waves, 2 blocks/CU.
__global__ __launch_bounds__(256, 2) void chamfer_mfma(
    const float* __restrict__ tpl, const float* __restrict__ src,
    const _Float16* __restrict__ arow, float* __restrict__ blocksum,
    float* __restrict__ out) {
    __shared__ uint4 sbuf[2][1024];   // 2 x 16 KB chunk buffers
    __shared__ float wsum[4];

    const int tid = threadIdx.x;
    const int wv = tid >> 6, lane = tid & 63;
    const int n = lane & 31, g = lane >> 5;           // B col / K-half group
    // --- XCD-locality remap (bijection on [0,512)) -- kept from R14 ---
    const int lin = blockIdx.x + 16 * (blockIdx.y + 16 * blockIdx.z);
    const int s_  = lin >> 3;
    const int qb  = s_ & 15;
    const int region = (lin & 7) + 8 * (s_ >> 4);     // region -> 1 XCD
    const int batch  = region & 15;
    const int dir    = region >> 4;

    const float* qpts = (dir == 0) ? src : tpl;       // dist1: query = source
    const _Float16* abase = arow + ((dir == 0) ? (size_t)0 : (size_t)65536 * 16)
                          + (size_t)batch * 4096 * 16;

    // Eight B fragments (frag f -> query qb*256 + f*32 + n) + |p|^2.
    f16x8 bfr[8];
    float p2[8];
    #pragma unroll
    for (int f = 0; f < 8; ++f) {
        const int q = qb * 256 + f * 32 + n;
        const float* p = qpts + (size_t)(batch * 4096 + q) * 3;
        float px = p[0], py = p[1], pz = p[2];
        p2[f] = fmaf(px, px, fmaf(py, py, pz * pz));
        _Float16 xh = (_Float16)px, yh = (_Float16)py, zh = (_Float16)pz;
        _Float16 xl = (_Float16)(px - (float)xh);
        _Float16 yl = (_Float16)(py - (float)yh);
        _Float16 zl = (_Float16)(pz - (float)pz + (float)(pz - (float)zh));
        zl = (_Float16)(pz - (float)zh);
        f16x8 b;
        if (g == 0) {
            b[0] = xh; b[1] = yh; b[2] = zh;
            b[3] = xh; b[4] = yh; b[5] = zh;
            b[6] = xl; b[7] = yl;
        } else {
            b[0] = zl; b[1] = (_Float16)1.0f; b[2] = (_Float16)1.0f;
            b[3] = (_Float16)0.0f; b[4] = (_Float16)0.0f; b[5] = (_Float16)0.0f;
            b[6] = (_Float16)0.0f; b[7] = (_Float16)0.0f;
        }
        bfr[f] = b;
    }

    const int lane_off = n * 32 + g * 16;
    // Wave reads ONLY its own quarter: sbuf[buf] + wv*4096 (+ tile*1024).
    const unsigned dsa0 = (unsigned)(size_t)((AS3 char*)&sbuf[0][0]) + wv * 4096 + lane_off;
    const unsigned dsa1 = (unsigned)(size_t)((AS3 char*)&sbuf[1][0]) + wv * 4096 + lane_off;

    // Wave's staging share == its read quarter: 4 KB, 4 x 1 KB load_lds.
    const char* gwave = (const char*)abase + wv * 4096 + lane * 16;
    #define STAGE(ch)                                                          \
        {                                                                      \
            const char* gp = gwave + (size_t)(ch) * 16384;                     \
            AS3 char* lp = (AS3 char*)&sbuf[(ch) & 1][0] + wv * 4096;          \
            _Pragma("unroll")                                                  \
            for (int j = 0; j < 4; ++j)                                        \
                __builtin_amdgcn_global_load_lds(                              \
                    (const AS1 unsigned*)(gp + j * 1024),                      \
                    (AS3 unsigned*)(lp + j * 1024), 16, 0, 0);                 \
        }

    float acc0 = 1e30f, acc1 = 1e30f, acc2 = 1e30f, acc3 = 1e30f;
    float acc4 = 1e30f, acc5 = 1e30f, acc6 = 1e30f, acc7 = 1e30f;
    float acc8 = 1e30f, acc9 = 1e30f, acc10 = 1e30f, acc11 = 1e30f;
    float acc12 = 1e30f, acc13 = 1e30f, acc14 = 1e30f, acc15 = 1e30f;
    f16x8 d0, d1, d2, d3;

    STAGE(0)
    #pragma unroll 1
    for (int c = 0; c < 8; ++c) {
        if (c < 7) {
            STAGE(c + 1)
            asm volatile("s_waitcnt vmcnt(4)" ::: "memory");   // own quarter ready
        } else {
            asm volatile("s_waitcnt vmcnt(0)" ::: "memory");
        }
        const unsigned dsa = (c & 1) ? dsa1 : dsa0;

        asm volatile(
            ZM(96) ZM(97) ZM(98) ZM(99) ZM(100) ZM(101) ZM(102) ZM(103)
            ZM(104) ZM(105) ZM(106) ZM(107) ZM(108) ZM(109) ZM(110) ZM(111)
            DSR(d0,0) DSR(d1,1024) DSR(d2,2048) DSR(d3,3072)
            TILE(d0,3)
            TILE(d1,2)
            TILE(d2,1)
            TILE(d3,0)
            : [d0]"=&v"(d0), [d1]"=&v"(d1), [d2]"=&v"(d2), [d3]"=&v"(d3),
              [acc0]"+v"(acc0),   [acc1]"+v"(acc1),
              [acc2]"+v"(acc2),   [acc3]"+v"(acc3),
              [acc4]"+v"(acc4),   [acc5]"+v"(acc5),
              [acc6]"+v"(acc6),   [acc7]"+v"(acc7),
              [acc8]"+v"(acc8),   [acc9]"+v"(acc9),
              [acc10]"+v"(acc10), [acc11]"+v"(acc11),
              [acc12]"+v"(acc12), [acc13]"+v"(acc13),
              [acc14]"+v"(acc14), [acc15]"+v"(acc15)
            : [bf0]"v"(bfr[0]), [bf1]"v"(bfr[1]), [bf2]"v"(bfr[2]),
              [bf3]"v"(bfr[3]), [bf4]"v"(bfr[4]), [bf5]"v"(bfr[5]),
              [bf6]"v"(bfr[6]), [bf7]"v"(bfr[7]), [dsa]"v"(dsa)
            : "memory",
              "v32","v33","v34","v35","v36","v37","v38","v39",
              "v40","v41","v42","v43","v44","v45","v46","v47",
              "v48","v49","v50","v51","v52","v53","v54","v55",
              "v56","v57","v58","v59","v60","v61","v62","v63",
              "v64","v65","v66","v67","v68","v69","v70","v71",
              "v72","v73","v74","v75","v76","v77","v78","v79",
              "v80","v81","v82","v83","v84","v85","v86","v87",
              "v88","v89","v90","v91","v92","v93","v94","v95",
              "v96","v97","v98","v99","v100","v101","v102","v103",
              "v104","v105","v106","v107","v108","v109","v110","v111");
        // No barrier: wave re-stages only its own quarter, and its own
        // ds_reads were drained by TILE(d3,0)'s lgkmcnt(0).
    }

    // Per-frag: rows split across lane halves -> fold g-halves in-wave.
    float m0 = fminf(acc0,  acc1);  m0 = fminf(m0, __shfl_xor(m0, 32));
    float m1 = fminf(acc2,  acc3);  m1 = fminf(m1, __shfl_xor(m1, 32));
    float m2 = fminf(acc4,  acc5);  m2 = fminf(m2, __shfl_xor(m2, 32));
    float m3 = fminf(acc6,  acc7);  m3 = fminf(m3, __shfl_xor(m3, 32));
    float m4 = fminf(acc8,  acc9);  m4 = fminf(m4, __shfl_xor(m4, 32));
    float m5 = fminf(acc10, acc11); m5 = fminf(m5, __shfl_xor(m5, 32));
    float m6 = fminf(acc12, acc13); m6 = fminf(m6, __shfl_xor(m6, 32));
    float m7 = fminf(acc14, acc15); m7 = fminf(m7, __shfl_xor(m7, 32));

    __syncthreads();                       // all waves done with sbuf; reuse it
    float* cs = (float*)&sbuf[0][0];       // cmin[4][8][32] + p2s[8][32]
    if (g == 0) {
        float* cw = cs + wv * 256 + n;
        cw[0] = m0;  cw[32] = m1;  cw[64] = m2;  cw[96] = m3;
        cw[128] = m4; cw[160] = m5; cw[192] = m6; cw[224] = m7;
    }
    if (tid < 32) {                        // wave 0, g==0: stash |p|^2 per query
        float* cp = cs + 1024 + n;
        #pragma unroll
        for (int f = 0; f < 8; ++f) cp[f * 32] = p2[f];
    }
    __syncthreads();

    // One query per lane: f = wv*2 + g, col = n. Min over the 4 A-quarters.
    {
        const int f = wv * 2 + g;
        const float* cr = cs + f * 32 + n;
        float mm = fminf(fminf(cr[0], cr[256]), fminf(cr[512], cr[768]));
        float dd = fmaxf(mm + cr[1024], 0.0f);
        float s = sqrtf(dd) * INV_CNT;
        #pragma unroll
        for (int off = 32; off > 0; off >>= 1) s += __shfl_down(s, off);
        if (lane == 0) wsum[wv] = s;
    }
    __syncthreads();
    if (tid == 0) {
        float t = wsum[0] + wsum[1] + wsum[2] + wsum[3];
        if (blocksum) {
            int flat = (dir * N_BATCH + batch) * 16 + qb;   // remapped coords
            blocksum[flat] = t;                        // unique slot: no atomics
        } else {
            atomicAdd(out, t);                         // fallback (small ws)
        }
    }
}

// Reduce 512 block sums -> out[0]. Single block, no atomics.
__global__ __launch_bounds__(256) void final_kernel(
    const float* __restrict__ blocksum, float* __restrict__ out) {
    __shared__ float wsum[4];
    float s = 0.0f;
    #pragma unroll
    for (int j = 0; j < NBLK / 256; ++j)
        s += blocksum[j * 256 + threadIdx.x];
    #pragma unroll
    for (int off = 32; off > 0; off >>= 1) s += __shfl_down(s, off);
    if ((threadIdx.x & 63) == 0) wsum[threadIdx.x >> 6] = s;
    __syncthreads();
    if (threadIdx.x == 0) out[0] = wsum[0] + wsum[1] + wsum[2] + wsum[3];
}

extern "C" void kernel_launch(void* const* d_in, const int* in_sizes, int n_in,
                              void* d_out, int out_size, void* d_ws, size_t ws_size,
                              hipStream_t stream) {
    const float* tpl = (const float*)d_in[0];
    const float* src = (const float*)d_in[1];
    float* out = (float*)d_out;
    _Float16* arow = (_Float16*)d_ws;                  // 4 MB
    const bool roomy = ws_size >= AROW_BYTES + NBLK * sizeof(float);
    float* blocksum = roomy ? (float*)((char*)d_ws + AROW_BYTES) : nullptr;

    hipLaunchKernelGGL(prep_kernel, dim3((2 * N_BATCH * N_PTS) / 256),
                       dim3(256), 0, stream, tpl, src, arow, out);
    dim3 grid(N_PTS / 256, N_BATCH, 2);                // (16, 16, 2) = 512 blocks
    hipLaunchKernelGGL(chamfer_mfma, grid, dim3(256), 0, stream,
                       tpl, src, arow, blocksum, out);
    if (roomy)
        hipLaunchKernelGGL(final_kernel, dim3(1), dim3(256), 0, stream,
                           blocksum, out);
}

// Round 2
// 77.168 us; speedup vs baseline: 1.0194x; 1.0194x over previous
//
#include <hip/hip_runtime.h>

#define N_PTS   4096
#define N_BATCH 16
#define INV_CNT (1.0f / (2.0f * N_BATCH * N_PTS))

typedef _Float16 f16x8  __attribute__((ext_vector_type(8)));
#define AS3 __attribute__((address_space(3)))

// 32x32x16 f16 MFMA, K-slot packing (split o = oh + ol, p = ph + pl in f16):
//   A-row (opposite point o): [-2oh_x,-2oh_y,-2oh_z, -2ol_x,-2ol_y,-2ol_z,
//                              -2oh_x,-2oh_y | -2oh_z, o2h, o2l, 0...]
//   B-col (query p):          [ph_x,ph_y,ph_z, ph_x,ph_y,ph_z, pl_x,pl_y |
//                              pl_z, 1, 1, 0...]
//   => C = |o|^2 - 2 o.p   (dropped ol.pl ~2^-22; verified R5-R14, absmax 0.0)
//
// R16: FUSED single kernel. prep_kernel is gone -- each block packs its own
// (dir,batch) A-region chunk-by-chunk into LDS (512 pts/chunk, 2 pts/thread,
// ~44 VALU/thread -- amortized across all 4 waves). final_kernel is gone --
// per-block partials go through one atomicAdd; d_out zeroed by a 4-byte
// hipMemsetAsync. Compute body is the verbatim R0/R14 16-t-step pipeline
// (proven 74.9us) -- R15's transposed mapping regressed and is reverted.

__device__ inline void pack_pt(float x, float y, float z, AS3 _Float16* lp) {
    float o2 = fmaf(x, x, fmaf(y, y, z * z));
    _Float16 xh = (_Float16)x, yh = (_Float16)y, zh = (_Float16)z;
    _Float16 xl = (_Float16)(x - (float)xh);
    _Float16 yl = (_Float16)(y - (float)yh);
    _Float16 zl = (_Float16)(z - (float)zh);
    _Float16 o2h = (_Float16)o2;
    _Float16 o2l = (_Float16)(o2 - (float)o2h);
    const _Float16 m2 = (_Float16)-2.0f;              // exact power-of-2 scale
    f16x8 v0, v1;
    v0[0] = m2 * xh; v0[1] = m2 * yh; v0[2] = m2 * zh;
    v0[3] = m2 * xl; v0[4] = m2 * yl; v0[5] = m2 * zl;
    v0[6] = m2 * xh; v0[7] = m2 * yh;
    v1[0] = m2 * zh; v1[1] = o2h; v1[2] = o2l;
    v1[3] = (_Float16)0.0f; v1[4] = (_Float16)0.0f; v1[5] = (_Float16)0.0f;
    v1[6] = (_Float16)0.0f; v1[7] = (_Float16)0.0f;
    *(AS3 f16x8*)lp       = v0;
    *(AS3 f16x8*)(lp + 8) = v1;
}

// ---- asm body (chunk-local register state only). Banks: A = v[32:47]
// (frag0) + v[64:79] (frag1); B = v[48:63] + v[80:95]; zero-C = v[96:111],
// re-zeroed per chunk. Identical to the proven R0/R14 schedule. ----
#define FD(a,x,y) "v_min3_f32 %[" #a "], v" #x ", v" #y ", %[" #a "]\n\t"
#define FOLD_A FD(acc0,32,33) FD(acc1,34,35) FD(acc0,36,37) FD(acc1,38,39) \
               FD(acc0,40,41) FD(acc1,42,43) FD(acc0,44,45) FD(acc1,46,47) \
               FD(acc2,64,65) FD(acc3,66,67) FD(acc2,68,69) FD(acc3,70,71) \
               FD(acc2,72,73) FD(acc3,74,75) FD(acc2,76,77) FD(acc3,78,79)
#define FOLD_B FD(acc0,48,49) FD(acc1,50,51) FD(acc0,52,53) FD(acc1,54,55) \
               FD(acc0,56,57) FD(acc1,58,59) FD(acc0,60,61) FD(acc1,62,63) \
               FD(acc2,80,81) FD(acc3,82,83) FD(acc2,84,85) FD(acc3,86,87) \
               FD(acc2,88,89) FD(acc3,90,91) FD(acc2,92,93) FD(acc3,94,95)
#define MF_A(d) \
  "v_mfma_f32_32x32x16_f16 v[32:47], %[" #d "], %[bf0], v[96:111]\n\t" \
  "v_mfma_f32_32x32x16_f16 v[64:79], %[" #d "], %[bf1], v[96:111]\n\t"
#define MF_B(d) \
  "v_mfma_f32_32x32x16_f16 v[48:63], %[" #d "], %[bf0], v[96:111]\n\t" \
  "v_mfma_f32_32x32x16_f16 v[80:95], %[" #d "], %[bf1], v[96:111]\n\t"
#define DSR(d,off) "ds_read_b128 %[" #d "], %[dsa] offset:" #off "\n\t"
#define WL(n) "s_waitcnt lgkmcnt(" #n ")\n\t"
#define ZM(r) "v_mov_b32 v" #r ", 0\n\t"
#define NOP3 "s_nop 7\n\t" "s_nop 7\n\t" "s_nop 7\n\t"

// Grid (16,16,2) = 512 blocks x 4 waves, 2 blocks/CU.
__global__ __launch_bounds__(256, 2) void chamfer_fused(
    const float* __restrict__ tpl, const float* __restrict__ src,
    float* __restrict__ out) {
    __shared__ uint4 sbuf[2][1024];   // 2 x 16 KB packed-A chunk buffers
    __shared__ float wsum[4];

    const int tid = threadIdx.x;
    const int wv = tid >> 6, lane = tid & 63;
    const int n = lane & 31, g = lane >> 5;           // B col / K-half group
    // --- XCD-locality remap (bijection on [0,512)) -- kept from R14 ---
    const int lin = blockIdx.x + 16 * (blockIdx.y + 16 * blockIdx.z);
    const int s_  = lin >> 3;
    const int qb  = s_ & 15;
    const int region = (lin & 7) + 8 * (s_ >> 4);     // region -> 1 XCD
    const int batch  = region & 15;
    const int dir    = region >> 4;

    const float* qpts = (dir == 0) ? src : tpl;       // dist1: query = source
    const float* araw = ((dir == 0) ? tpl : src)      // raw opposite-set slice
                      + (size_t)batch * 4096 * 3;

    // Two B fragments (frag i -> query qb*256 + wv*64 + i*32 + n) + |p|^2.
    f16x8 bfr[2];
    float p2[2];
    #pragma unroll
    for (int i = 0; i < 2; ++i) {
        const int q = qb * 256 + wv * 64 + i * 32 + n;
        const float* p = qpts + (size_t)(batch * 4096 + q) * 3;
        float px = p[0], py = p[1], pz = p[2];
        p2[i] = fmaf(px, px, fmaf(py, py, pz * pz));
        _Float16 xh = (_Float16)px, yh = (_Float16)py, zh = (_Float16)pz;
        _Float16 xl = (_Float16)(px - (float)xh);
        _Float16 yl = (_Float16)(py - (float)yh);
        _Float16 zl = (_Float16)(pz - (float)zh);
        f16x8 b;
        if (g == 0) {
            b[0] = xh; b[1] = yh; b[2] = zh;
            b[3] = xh; b[4] = yh; b[5] = zh;
            b[6] = xl; b[7] = yl;
        } else {
            b[0] = zl; b[1] = (_Float16)1.0f; b[2] = (_Float16)1.0f;
            b[3] = (_Float16)0.0f; b[4] = (_Float16)0.0f; b[5] = (_Float16)0.0f;
            b[6] = (_Float16)0.0f; b[7] = (_Float16)0.0f;
        }
        bfr[i] = b;
    }

    const int lane_off = n * 32 + g * 16;
    const unsigned dsa0 = (unsigned)(size_t)((AS3 char*)&sbuf[0][0]) + lane_off;
    const unsigned dsa1 = (unsigned)(size_t)((AS3 char*)&sbuf[1][0]) + lane_off;

    // Chunk staging: thread t packs points {t, t+256} of the 512-pt chunk
    // (stride-32B layout -> 4-way-max write conflicts, ~64 cyc/chunk/wave).
    // Raw loads are issued one chunk ahead (T14 issue-early/use-late); the
    // pack consumes them at the top of the next iteration.
    float r0, r1, r2, r3, r4, r5;
    #define ALOAD(ch)                                                          \
        {                                                                      \
            const float* gp = araw + (size_t)(ch) * 1536 + tid * 3;            \
            r0 = gp[0]; r1 = gp[1]; r2 = gp[2];                                \
            r3 = gp[768]; r4 = gp[769]; r5 = gp[770];                          \
        }
    #define APACK(ch)                                                          \
        {                                                                      \
            AS3 _Float16* lp = (AS3 _Float16*)&sbuf[(ch) & 1][0];              \
            pack_pt(r0, r1, r2, lp + tid * 16);                                \
            pack_pt(r3, r4, r5, lp + (tid + 256) * 16);                        \
        }

    float acc0 = 1e30f, acc1 = 1e30f, acc2 = 1e30f, acc3 = 1e30f;
    f16x8 d0, d1, d2, d3;

    ALOAD(0)
    APACK(0)
    ALOAD(1)                               // prefetch chunk 1
    __syncthreads();                       // chunk 0 visible to all waves

    #pragma unroll 1
    for (int c = 0; c < 8; ++c) {
        if (c < 7) {
            APACK(c + 1)                   // write next buf (parity ~c) ...
            if (c < 6) ALOAD(c + 2)        // ... and prefetch the one after
        }
        const unsigned dsa = (c & 1) ? dsa1 : dsa0;

        asm volatile(
            ZM(96) ZM(97) ZM(98) ZM(99) ZM(100) ZM(101) ZM(102) ZM(103)
            ZM(104) ZM(105) ZM(106) ZM(107) ZM(108) ZM(109) ZM(110) ZM(111)
            DSR(d0,0) DSR(d1,1024) DSR(d2,2048) DSR(d3,3072)
            // t0 (A banks, no fold; NOP3 protects t1's fold of t0's D).
            // WL(3) also drains this wave's 4 pack ds_writes (in-order queue).
            WL(3) MF_A(d0) DSR(d0,4096) NOP3
            WL(3) MF_B(d1) DSR(d1,5120)  FOLD_A      // t1
            WL(3) MF_A(d2) DSR(d2,6144)  FOLD_B      // t2
            WL(3) MF_B(d3) DSR(d3,7168)  FOLD_A      // t3
            WL(3) MF_A(d0) DSR(d0,8192)  FOLD_B      // t4
            WL(3) MF_B(d1) DSR(d1,9216)  FOLD_A      // t5
            WL(3) MF_A(d2) DSR(d2,10240) FOLD_B      // t6
            WL(3) MF_B(d3) DSR(d3,11264) FOLD_A      // t7
            WL(3) MF_A(d0) DSR(d0,12288) FOLD_B      // t8
            WL(3) MF_B(d1) DSR(d1,13312) FOLD_A      // t9
            WL(3) MF_A(d2) DSR(d2,14336) FOLD_B      // t10
            WL(3) MF_B(d3) DSR(d3,15360) FOLD_A      // t11
            WL(3) MF_A(d0) FOLD_B                    // t12
            WL(2) MF_B(d1) FOLD_A                    // t13
            WL(1) MF_A(d2) FOLD_B                    // t14
            WL(0) MF_B(d3) FOLD_A                    // t15
            NOP3 FOLD_B                              // tail: t15's D
            : [d0]"=&v"(d0), [d1]"=&v"(d1), [d2]"=&v"(d2), [d3]"=&v"(d3),
              [acc0]"+v"(acc0), [acc1]"+v"(acc1),
              [acc2]"+v"(acc2), [acc3]"+v"(acc3)
            : [bf0]"v"(bfr[0]), [bf1]"v"(bfr[1]), [dsa]"v"(dsa)
            : "memory",
              "v32","v33","v34","v35","v36","v37","v38","v39",
              "v40","v41","v42","v43","v44","v45","v46","v47",
              "v48","v49","v50","v51","v52","v53","v54","v55",
              "v56","v57","v58","v59","v60","v61","v62","v63",
              "v64","v65","v66","v67","v68","v69","v70","v71",
              "v72","v73","v74","v75","v76","v77","v78","v79",
              "v80","v81","v82","v83","v84","v85","v86","v87",
              "v88","v89","v90","v91","v92","v93","v94","v95",
              "v96","v97","v98","v99","v100","v101","v102","v103",
              "v104","v105","v106","v107","v108","v109","v110","v111");

        // One barrier/chunk: separates this iter's writes of chunk c+1 from
        // next iter's reads, and this iter's reads of chunk c from the
        // write of chunk c+2. asm ended lgkmcnt(0) -> all DS ops retired.
        if (c < 7) __syncthreads();
    }

    // Per-frag: rows split across lane halves; fold, clamp, sqrt.
    float v0 = fminf(acc0, acc1);
    v0 = fminf(v0, __shfl_xor(v0, 32));
    float v1 = fminf(acc2, acc3);
    v1 = fminf(v1, __shfl_xor(v1, 32));
    float dd0 = fmaxf(v0 + p2[0], 0.0f);               // == min of clamped
    float dd1 = fmaxf(v1 + p2[1], 0.0f);
    float s = (sqrtf(dd0) + sqrtf(dd1)) * INV_CNT;
    if (g != 0) s = 0.0f;                              // count each query once
    #pragma unroll
    for (int off = 32; off > 0; off >>= 1) s += __shfl_down(s, off);
    if (lane == 0) wsum[wv] = s;
    __syncthreads();
    if (tid == 0)
        atomicAdd(out, wsum[0] + wsum[1] + wsum[2] + wsum[3]);
}

extern "C" void kernel_launch(void* const* d_in, const int* in_sizes, int n_in,
                              void* d_out, int out_size, void* d_ws, size_t ws_size,
                              hipStream_t stream) {
    const float* tpl = (const float*)d_in[0];
    const float* src = (const float*)d_in[1];
    float* out = (float*)d_out;
    (void)d_ws; (void)ws_size; (void)in_sizes; (void)n_in; (void)out_size;

    hipMemsetAsync(out, 0, sizeof(float), stream);     // 4 B, graph-capturable
    dim3 grid(N_PTS / 256, N_BATCH, 2);                // (16, 16, 2) = 512 blocks
    hipLaunchKernelGGL(chamfer_fused, grid, dim3(256), 0, stream,
                       tpl, src, out);
}